// Round 12
// baseline (108.379 us; speedup 1.0000x reference)
//
#include <hip/hip_runtime.h>

#define B_  4
#define Q_  512
#define K_  1024
#define D_  256
#define VD_ 256
#define H_  128
#define NK_ (B_*K_)   // 4096 global key rows

// tanh(x) = 1 - 2/(1 + e^{2x});  e^{2(q+k)} = Eq*Ek,  Eq = exp2(CE*q)
constexpr float CE  = 2.8853900817779268f;   // 2*log2(e)
constexpr float L2E = 1.4426950408889634f;

__device__ __forceinline__ float arcp(float x) { return __builtin_amdgcn_rcpf(x); }

// ---------------- projection ----------------
// 768 blocks x 256 thr, 8 rows each. wg<512: keys -> EkT2 packed [h/4][kglob][4]
// (LDS transpose -> coalesced stores); fully-invalid key groups early-exit.
// wg>=512: queries -> Eq row-major [q][h].
__global__ __launch_bounds__(256) void proj_kernel(
    const float* __restrict__ keys, const float* __restrict__ queries,
    const float* __restrict__ Wk, const float* __restrict__ Wq,
    const int* __restrict__ vlens,
    float* __restrict__ EkT2, float* __restrict__ Eq)
{
    __shared__ __align__(16) float Xs[8 * D_];    // 8 KB
    __shared__ __align__(16) float Es[8][132];    // padded transpose buffer
    const int tid = threadIdx.x;
    const int wg  = blockIdx.x;
    const bool isK = (wg < 512);

    if (isK) {  // early-exit for fully-invalid key groups
        const int kb  = wg >> 7;                       // batch of these 8 keys
        const int n_b = ((vlens[kb] + 255) >> 8) << 8; // attn reads k < n_b only
        if ((int)((wg << 3) & (K_ - 1)) >= n_b) return;
    }

    const float* X = isK ? (keys + (size_t)wg * 8 * D_)
                         : (queries + (size_t)(wg - 512) * 8 * D_);
    const float* W = isK ? Wk : Wq;

    { // stage X: 2048 floats = 512 float4
        const float4* xg = (const float4*)X;
        ((float4*)Xs)[tid]       = xg[tid];
        ((float4*)Xs)[tid + 256] = xg[tid + 256];
    }
    __syncthreads();

    const int c    = tid & 127;
    const int half = tid >> 7;                    // wave-uniform: rows half*4..+3
    const float* xb = Xs + half * 4 * D_;
    float a0 = 0.f, a1 = 0.f, a2 = 0.f, a3 = 0.f;
    #pragma unroll 4
    for (int d = 0; d < D_; d += 4) {
        float w0 = W[(d+0)*H_ + c];
        float w1 = W[(d+1)*H_ + c];
        float w2 = W[(d+2)*H_ + c];
        float w3 = W[(d+3)*H_ + c];
        float4 x0 = *(const float4*)(xb + 0*D_ + d);   // LDS broadcast
        float4 x1 = *(const float4*)(xb + 1*D_ + d);
        float4 x2 = *(const float4*)(xb + 2*D_ + d);
        float4 x3 = *(const float4*)(xb + 3*D_ + d);
        a0 = fmaf(x0.x,w0,a0); a0 = fmaf(x0.y,w1,a0); a0 = fmaf(x0.z,w2,a0); a0 = fmaf(x0.w,w3,a0);
        a1 = fmaf(x1.x,w0,a1); a1 = fmaf(x1.y,w1,a1); a1 = fmaf(x1.z,w2,a1); a1 = fmaf(x1.w,w3,a1);
        a2 = fmaf(x2.x,w0,a2); a2 = fmaf(x2.y,w1,a2); a2 = fmaf(x2.z,w2,a2); a2 = fmaf(x2.w,w3,a2);
        a3 = fmaf(x3.x,w0,a3); a3 = fmaf(x3.y,w1,a3); a3 = fmaf(x3.z,w2,a3); a3 = fmaf(x3.w,w3,a3);
    }
    a0 = exp2f(a0 * CE); a1 = exp2f(a1 * CE);
    a2 = exp2f(a2 * CE); a3 = exp2f(a3 * CE);

    if (isK) {
        const int r4 = half * 4;
        Es[r4+0][c] = a0; Es[r4+1][c] = a1; Es[r4+2][c] = a2; Es[r4+3][c] = a3;
        __syncthreads();
        // coalesced packed store: thread -> (h4 = tid>>3, r = tid&7)
        const int h4 = tid >> 3;
        const int r  = tid & 7;
        float4 v = *(const float4*)&Es[r][h4 * 4];
        const int kg = wg * 8 + r;
        *(float4*)(EkT2 + (size_t)h4 * (NK_*4) + (size_t)kg * 4) = v;
    } else {
        const int r0 = (wg - 512) * 8 + half * 4;
        Eq[(size_t)(r0+0)*H_ + c] = a0;
        Eq[(size_t)(r0+1)*H_ + c] = a1;
        Eq[(size_t)(r0+2)*H_ + c] = a2;
        Eq[(size_t)(r0+3)*H_ + c] = a3;
    }
}

// ---------------- fused scores -> exp -> PV, WAVE-FUSED ----------------
// grid 512 x 1024 thr (16 waves; 2 blocks/CU = 32 waves/CU). LPT batch remap.
// KEY CHANGE vs R11: wave w owns keys [64w,64w+64) for BOTH score compute and
// PV sweep -> the A->B dependency is wave-local (scores flow through the
// wave's own S chunk, ordered by lgkmcnt; NO __syncthreads between phases).
// Waves run A+B back-to-back independently: one wave's PV VMEM overlaps other
// waves' TERM VALU. Only the 3 cheap tree-combine barriers remain.
#define TERMP(ACC, W0, W1, E0, E1, Q0, Q1) { \
    float _a = fmaf(E0, Q0, 1.0f); float _b = fmaf(E1, Q1, 1.0f); \
    float _num = fmaf(W1, _a, W0 * _b); \
    ACC = fmaf(_num, arcp(_a * _b), ACC); }
#define PVA(OO, P, V) { OO.x = fmaf(P, V.x, OO.x); OO.y = fmaf(P, V.y, OO.y); \
                        OO.z = fmaf(P, V.z, OO.z); OO.w = fmaf(P, V.w, OO.w); }
#define ACC4(OO, P) { float4 _p = P; OO.x += _p.x; OO.y += _p.y; OO.z += _p.z; OO.w += _p.w; }
#define PVBLK4 { \
    float4 p0 = *(const float4*)&S[0][i]; \
    float4 p1 = *(const float4*)&S[1][i]; \
    float4 p2 = *(const float4*)&S[2][i]; \
    float4 p3 = *(const float4*)&S[3][i]; \
    PVA(o0,p0.x,va) PVA(o0,p0.y,vb) PVA(o0,p0.z,vc) PVA(o0,p0.w,vd) \
    PVA(o1,p1.x,va) PVA(o1,p1.y,vb) PVA(o1,p1.z,vc) PVA(o1,p1.w,vd) \
    PVA(o2,p2.x,va) PVA(o2,p2.y,vb) PVA(o2,p2.z,vc) PVA(o2,p2.w,vd) \
    PVA(o3,p3.x,va) PVA(o3,p3.y,vb) PVA(o3,p3.z,vc) PVA(o3,p3.w,vd) }
#define QUAD(E4) { \
    float4 wv4 = *(const float4*)&msc[h4*4]; \
    float4 v0  = *(const float4*)&Eq_s[0][h4*4]; \
    float4 v1  = *(const float4*)&Eq_s[1][h4*4]; \
    float4 v2  = *(const float4*)&Eq_s[2][h4*4]; \
    float4 v3  = *(const float4*)&Eq_s[3][h4*4]; \
    TERMP(a0, wv4.x, wv4.y, E4.x, E4.y, v0.x, v0.y); \
    TERMP(a0, wv4.z, wv4.w, E4.z, E4.w, v0.z, v0.w); \
    TERMP(a1, wv4.x, wv4.y, E4.x, E4.y, v1.x, v1.y); \
    TERMP(a1, wv4.z, wv4.w, E4.z, E4.w, v1.z, v1.w); \
    TERMP(a2, wv4.x, wv4.y, E4.x, E4.y, v2.x, v2.y); \
    TERMP(a2, wv4.z, wv4.w, E4.z, E4.w, v2.z, v2.w); \
    TERMP(a3, wv4.x, wv4.y, E4.x, E4.y, v3.x, v3.y); \
    TERMP(a3, wv4.z, wv4.w, E4.z, E4.w, v3.z, v3.w); }
#define CSWP(A,B) { if (A < B) { int _t = A; A = B; B = _t; } }

__global__ __launch_bounds__(1024, 8) void attn_kernel(
    const float* __restrict__ Eq, const float* __restrict__ EkT2,
    const float* __restrict__ wv, const float* __restrict__ values,
    const int* __restrict__ vlens, float* __restrict__ out)
{
    __shared__ __align__(16) float S[4][K_];           // 16 KB exp'd scores
    __shared__ __align__(16) float OP[8][4][VD_/4][4]; // 32 KB tree-combine buffer
    __shared__ __align__(16) float Eq_s[4][H_];        // 2 KB
    __shared__ __align__(16) float msc[H_];            // 0.5 KB
    __shared__ float SL[16][4];                        // per-wave denom partials
    const int tid = threadIdx.x;
    const int wg  = blockIdx.x;

    // ---- LPT batch remap: sort batches by descending n (deterministic) ----
    int c0 = ((((vlens[0] + 255) >> 8) << 8) << 2) | 0;
    int c1 = ((((vlens[1] + 255) >> 8) << 8) << 2) | 1;
    int c2 = ((((vlens[2] + 255) >> 8) << 8) << 2) | 2;
    int c3 = ((((vlens[3] + 255) >> 8) << 8) << 2) | 3;
    CSWP(c0,c1) CSWP(c2,c3) CSWP(c0,c2) CSWP(c1,c3) CSWP(c1,c2)
    const int rank = wg >> 7;                // 0 = longest n, dispatched first
    const int key  = rank == 0 ? c0 : rank == 1 ? c1 : rank == 2 ? c2 : c3;
    const int b    = key & 3;
    const int n    = key >> 2;               // 256..1024
    const int valid = vlens[b];
    const int q0   = (wg & 127) * 4;

    if (tid < 128) {
        msc[tid] = -2.0f * wv[tid];
        ((float4*)Eq_s)[tid] = ((const float4*)(Eq + (size_t)(b*Q_ + q0) * H_))[tid];
    }
    if (tid < 64) SL[tid >> 2][tid & 3] = 0.f;
    __syncthreads();

    const int w     = tid >> 6;
    const int lane  = tid & 63;
    const int kbase = w << 6;                // this wave's 64-key range
    float4 o0 = make_float4(0,0,0,0), o1 = o0, o2 = o0, o3 = o0;

    if (kbase < n) {                         // wave-uniform activity predicate
        // ---- phase A (wave-local): scores + exp + denom for keys [kbase,kbase+64) ----
        const int k = kbase + lane;          // == tid
        {
            const float4* ekp = (const float4*)EkT2 + (size_t)(b*K_ + k);
            float a0 = 0.f, a1 = 0.f, a2 = 0.f, a3 = 0.f;
            float4 e = ekp[0];
            #pragma unroll 4
            for (int h4 = 0; h4 < H_/4 - 1; ++h4) {
                float4 en = ekp[(size_t)(h4+1) * NK_];     // prefetch next
                QUAD(e)
                e = en;
            }
            {   // last h4 = 31
                const int h4 = H_/4 - 1;
                QUAD(e)
            }
            const bool ok = (k < valid);
            float p0 = ok ? exp2f(a0 * L2E) : 0.f;   // |score|<=2*sum|w_v| -> no max-sub
            float p1 = ok ? exp2f(a1 * L2E) : 0.f;
            float p2 = ok ? exp2f(a2 * L2E) : 0.f;
            float p3 = ok ? exp2f(a3 * L2E) : 0.f;
            S[0][k] = p0; S[1][k] = p1; S[2][k] = p2; S[3][k] = p3;
            #pragma unroll
            for (int off = 32; off > 0; off >>= 1) {
                p0 += __shfl_xor(p0, off, 64); p1 += __shfl_xor(p1, off, 64);
                p2 += __shfl_xor(p2, off, 64); p3 += __shfl_xor(p3, off, 64);
            }
            if (lane == 0) { SL[w][0] = p0; SL[w][1] = p1; SL[w][2] = p2; SL[w][3] = p3; }
        }

        // ---- phase B (wave-local, NO barrier): PV over own 64 keys ----
        // S reads below hit only this wave's own writes (compiler orders via lgkmcnt)
        const float4* vp = (const float4*)(values + (size_t)b * K_ * VD_);
        const float4* vr = vp + (size_t)kbase * (VD_/4) + lane;
        float4 va = vr[0], vb = vr[64], vc = vr[128], vd = vr[192];
        int i = kbase;
        for (; i < kbase + 60; i += 4) {
            const float4* vrn = vp + (size_t)(i + 4) * (VD_/4) + lane;
            float4 na = vrn[0], nb = vrn[64], nc = vrn[128], nd = vrn[192];
            PVBLK4
            va = na; vb = nb; vc = nc; vd = nd;
        }
        PVBLK4                               // final 4 keys
    }

    // ---- tree combine 16 -> 8 -> 4 -> store (race-free: self-slot rewrites) ----
    if (w >= 8) {                            // waves 8..15 -> slots 0..7
        *(float4*)&OP[w-8][0][lane][0] = o0;
        *(float4*)&OP[w-8][1][lane][0] = o1;
        *(float4*)&OP[w-8][2][lane][0] = o2;
        *(float4*)&OP[w-8][3][lane][0] = o3;
    }
    __syncthreads();
    if (w < 8) {                             // wave w adds slot w (own slot)
        ACC4(o0, (*(const float4*)&OP[w][0][lane][0]));
        ACC4(o1, (*(const float4*)&OP[w][1][lane][0]));
        ACC4(o2, (*(const float4*)&OP[w][2][lane][0]));
        ACC4(o3, (*(const float4*)&OP[w][3][lane][0]));
    }
    if (w >= 4 && w < 8) {                   // rewrite own slot (safe: self RAW)
        *(float4*)&OP[w][0][lane][0] = o0;
        *(float4*)&OP[w][1][lane][0] = o1;
        *(float4*)&OP[w][2][lane][0] = o2;
        *(float4*)&OP[w][3][lane][0] = o3;
    }
    __syncthreads();
    if (w < 4) {
        ACC4(o0, (*(const float4*)&OP[w+4][0][lane][0]));
        ACC4(o1, (*(const float4*)&OP[w+4][1][lane][0]));
        ACC4(o2, (*(const float4*)&OP[w+4][2][lane][0]));
        ACC4(o3, (*(const float4*)&OP[w+4][3][lane][0]));
        *(float4*)&OP[w][0][lane][0] = o0;   // own slot: only read by self this epoch
        *(float4*)&OP[w][1][lane][0] = o1;
        *(float4*)&OP[w][2][lane][0] = o2;
        *(float4*)&OP[w][3][lane][0] = o3;
    }
    __syncthreads();
    if (w < 4) {                             // wave w -> row w: sum 4 slots, scale, store
        const int row = w;
        float l = 0.f;
        #pragma unroll
        for (int s = 0; s < 16; ++s) l += SL[s][row];
        const float invl = arcp(l);
        float4 o = make_float4(0,0,0,0);
        #pragma unroll
        for (int s = 0; s < 4; ++s) {
            float4 p = *(const float4*)&OP[s][row][lane][0];
            o.x += p.x; o.y += p.y; o.z += p.z; o.w += p.w;
        }
        o.x *= invl; o.y *= invl; o.z *= invl; o.w *= invl;
        ((float4*)(out + (size_t)(b*Q_ + q0 + row) * VD_))[lane] = o;
    }
}

// ---------------- launch ----------------
extern "C" void kernel_launch(void* const* d_in, const int* in_sizes, int n_in,
                              void* d_out, int out_size, void* d_ws, size_t ws_size,
                              hipStream_t stream) {
    const float* queries = (const float*)d_in[0];
    const float* keys    = (const float*)d_in[1];
    const float* values  = (const float*)d_in[2];
    const int*   vlens   = (const int*)d_in[3];
    const float* W_q     = (const float*)d_in[4];
    const float* W_k     = (const float*)d_in[5];
    const float* w_v     = (const float*)d_in[6];
    float* out = (float*)d_out;
    float* ws  = (float*)d_ws;

    float* EkT2 = ws;            // (H/4) * NK_ * 4 = 524288 floats (packed)
    float* Eq   = ws + 524288;   // B*Q*H = 262144 floats

    proj_kernel<<<dim3(768), dim3(256), 0, stream>>>(keys, queries, W_k, W_q, vlens, EkT2, Eq);
    attn_kernel<<<dim3((B_*Q_)/4), dim3(1024), 0, stream>>>(Eq, EkT2, w_v, values, vlens, out);
}

// Round 13
// 106.810 us; speedup vs baseline: 1.0147x; 1.0147x over previous
//
#include <hip/hip_runtime.h>

#define B_  4
#define Q_  512
#define K_  1024
#define D_  256
#define VD_ 256
#define H_  128
#define NK_ (B_*K_)   // 4096 global key rows

// tanh(x) = 1 - 2/(1 + e^{2x});  e^{2(q+k)} = Eq*Ek,  Eq = exp2(CE*q)
constexpr float CE  = 2.8853900817779268f;   // 2*log2(e)
constexpr float L2E = 1.4426950408889634f;

__device__ __forceinline__ float arcp(float x) { return __builtin_amdgcn_rcpf(x); }

// ---------------- projection ----------------
// 768 blocks x 256 thr, 8 rows each. wg<512: keys -> EkT2 packed [h/4][kglob][4]
// (LDS transpose -> coalesced stores); blocks whose 8 keys all lie beyond the
// batch's rounded valid length n_b early-exit (attn never reads that range).
// wg>=512: queries -> Eq row-major [q][h].
__global__ __launch_bounds__(256) void proj_kernel(
    const float* __restrict__ keys, const float* __restrict__ queries,
    const float* __restrict__ Wk, const float* __restrict__ Wq,
    const int* __restrict__ vlens,
    float* __restrict__ EkT2, float* __restrict__ Eq)
{
    __shared__ __align__(16) float Xs[8 * D_];    // 8 KB
    __shared__ __align__(16) float Es[8][132];    // padded transpose buffer
    const int tid = threadIdx.x;
    const int wg  = blockIdx.x;
    const bool isK = (wg < 512);

    if (isK) {  // early-exit for fully-invalid key groups
        const int kb  = wg >> 7;                       // batch of these 8 keys
        const int n_b = ((vlens[kb] + 255) >> 8) << 8; // attn reads k < n_b only
        if ((int)((wg << 3) & (K_ - 1)) >= n_b) return;
    }

    const float* X = isK ? (keys + (size_t)wg * 8 * D_)
                         : (queries + (size_t)(wg - 512) * 8 * D_);
    const float* W = isK ? Wk : Wq;

    { // stage X: 2048 floats = 512 float4
        const float4* xg = (const float4*)X;
        ((float4*)Xs)[tid]       = xg[tid];
        ((float4*)Xs)[tid + 256] = xg[tid + 256];
    }
    __syncthreads();

    const int c    = tid & 127;
    const int half = tid >> 7;                    // wave-uniform: rows half*4..+3
    const float* xb = Xs + half * 4 * D_;
    float a0 = 0.f, a1 = 0.f, a2 = 0.f, a3 = 0.f;
    #pragma unroll 4
    for (int d = 0; d < D_; d += 4) {
        float w0 = W[(d+0)*H_ + c];
        float w1 = W[(d+1)*H_ + c];
        float w2 = W[(d+2)*H_ + c];
        float w3 = W[(d+3)*H_ + c];
        float4 x0 = *(const float4*)(xb + 0*D_ + d);   // LDS broadcast
        float4 x1 = *(const float4*)(xb + 1*D_ + d);
        float4 x2 = *(const float4*)(xb + 2*D_ + d);
        float4 x3 = *(const float4*)(xb + 3*D_ + d);
        a0 = fmaf(x0.x,w0,a0); a0 = fmaf(x0.y,w1,a0); a0 = fmaf(x0.z,w2,a0); a0 = fmaf(x0.w,w3,a0);
        a1 = fmaf(x1.x,w0,a1); a1 = fmaf(x1.y,w1,a1); a1 = fmaf(x1.z,w2,a1); a1 = fmaf(x1.w,w3,a1);
        a2 = fmaf(x2.x,w0,a2); a2 = fmaf(x2.y,w1,a2); a2 = fmaf(x2.z,w2,a2); a2 = fmaf(x2.w,w3,a2);
        a3 = fmaf(x3.x,w0,a3); a3 = fmaf(x3.y,w1,a3); a3 = fmaf(x3.z,w2,a3); a3 = fmaf(x3.w,w3,a3);
    }
    a0 = exp2f(a0 * CE); a1 = exp2f(a1 * CE);
    a2 = exp2f(a2 * CE); a3 = exp2f(a3 * CE);

    if (isK) {
        const int r4 = half * 4;
        Es[r4+0][c] = a0; Es[r4+1][c] = a1; Es[r4+2][c] = a2; Es[r4+3][c] = a3;
        __syncthreads();
        // coalesced packed store: thread -> (h4 = tid>>3, r = tid&7)
        const int h4 = tid >> 3;
        const int r  = tid & 7;
        float4 v = *(const float4*)&Es[r][h4 * 4];
        const int kg = wg * 8 + r;
        *(float4*)(EkT2 + (size_t)h4 * (NK_*4) + (size_t)kg * 4) = v;
    } else {
        const int r0 = (wg - 512) * 8 + half * 4;
        Eq[(size_t)(r0+0)*H_ + c] = a0;
        Eq[(size_t)(r0+1)*H_ + c] = a1;
        Eq[(size_t)(r0+2)*H_ + c] = a2;
        Eq[(size_t)(r0+3)*H_ + c] = a3;
    }
}

// ---------------- fused scores -> exp -> PV ----------------
// grid 512 x 1024 thr (16 waves; 2 blocks/CU = 32 waves/CU).
// LPT: batches sorted by descending n; rank = wg>>7 -> longest first;
// co-resident blocks {i,i+256} get ranks {r,r+2} (batch mixing + balance).
// Phase A: thread k; EkT2 b128 w/ next-iter prefetch; PAIR-2 rcp batching:
//   w0/a + w1/b = (w0*b + w1*a)*rcp(a*b) -> 1 trans per 2 terms.
// Phase B: 16 k-slices, 4 rows in regs, values once, prefetched; tree combine.
#define TERMP(ACC, W0, W1, E0, E1, Q0, Q1) { \
    float _a = fmaf(E0, Q0, 1.0f); float _b = fmaf(E1, Q1, 1.0f); \
    float _num = fmaf(W1, _a, W0 * _b); \
    ACC = fmaf(_num, arcp(_a * _b), ACC); }
#define PVA(OO, P, V) { OO.x = fmaf(P, V.x, OO.x); OO.y = fmaf(P, V.y, OO.y); \
                        OO.z = fmaf(P, V.z, OO.z); OO.w = fmaf(P, V.w, OO.w); }
#define ACC4(OO, P) { float4 _p = P; OO.x += _p.x; OO.y += _p.y; OO.z += _p.z; OO.w += _p.w; }
#define PVBLK4 { \
    float4 p0 = *(const float4*)&S[0][i]; \
    float4 p1 = *(const float4*)&S[1][i]; \
    float4 p2 = *(const float4*)&S[2][i]; \
    float4 p3 = *(const float4*)&S[3][i]; \
    PVA(o0,p0.x,va) PVA(o0,p0.y,vb) PVA(o0,p0.z,vc) PVA(o0,p0.w,vd) \
    PVA(o1,p1.x,va) PVA(o1,p1.y,vb) PVA(o1,p1.z,vc) PVA(o1,p1.w,vd) \
    PVA(o2,p2.x,va) PVA(o2,p2.y,vb) PVA(o2,p2.z,vc) PVA(o2,p2.w,vd) \
    PVA(o3,p3.x,va) PVA(o3,p3.y,vb) PVA(o3,p3.z,vc) PVA(o3,p3.w,vd) }
#define QUAD(E4) { \
    float4 wv4 = *(const float4*)&msc[h4*4]; \
    float4 v0  = *(const float4*)&Eq_s[0][h4*4]; \
    float4 v1  = *(const float4*)&Eq_s[1][h4*4]; \
    float4 v2  = *(const float4*)&Eq_s[2][h4*4]; \
    float4 v3  = *(const float4*)&Eq_s[3][h4*4]; \
    TERMP(a0, wv4.x, wv4.y, E4.x, E4.y, v0.x, v0.y); \
    TERMP(a0, wv4.z, wv4.w, E4.z, E4.w, v0.z, v0.w); \
    TERMP(a1, wv4.x, wv4.y, E4.x, E4.y, v1.x, v1.y); \
    TERMP(a1, wv4.z, wv4.w, E4.z, E4.w, v1.z, v1.w); \
    TERMP(a2, wv4.x, wv4.y, E4.x, E4.y, v2.x, v2.y); \
    TERMP(a2, wv4.z, wv4.w, E4.z, E4.w, v2.z, v2.w); \
    TERMP(a3, wv4.x, wv4.y, E4.x, E4.y, v3.x, v3.y); \
    TERMP(a3, wv4.z, wv4.w, E4.z, E4.w, v3.z, v3.w); }
#define CSWP(A,B) { if (A < B) { int _t = A; A = B; B = _t; } }

__global__ __launch_bounds__(1024, 8) void attn_kernel(
    const float* __restrict__ Eq, const float* __restrict__ EkT2,
    const float* __restrict__ wv, const float* __restrict__ values,
    const int* __restrict__ vlens, float* __restrict__ out)
{
    __shared__ __align__(16) float S[4][K_];           // 16 KB exp'd scores
    __shared__ __align__(16) float OP[8][4][VD_/4][4]; // 32 KB tree-combine buffer
    __shared__ __align__(16) float Eq_s[4][H_];        // 2 KB
    __shared__ __align__(16) float msc[H_];            // 0.5 KB
    __shared__ float SL[16][4];                        // per-wave denom partials
    const int tid = threadIdx.x;
    const int wg  = blockIdx.x;

    // ---- LPT batch remap: sort batches by descending n (deterministic) ----
    int c0 = ((((vlens[0] + 255) >> 8) << 8) << 2) | 0;
    int c1 = ((((vlens[1] + 255) >> 8) << 8) << 2) | 1;
    int c2 = ((((vlens[2] + 255) >> 8) << 8) << 2) | 2;
    int c3 = ((((vlens[3] + 255) >> 8) << 8) << 2) | 3;
    CSWP(c0,c1) CSWP(c2,c3) CSWP(c0,c2) CSWP(c1,c3) CSWP(c1,c2)
    const int rank = wg >> 7;                // 0 = longest n, dispatched first
    const int key  = rank == 0 ? c0 : rank == 1 ? c1 : rank == 2 ? c2 : c3;
    const int b    = key & 3;
    const int n    = key >> 2;               // 256..1024
    const int valid = vlens[b];
    const int q0   = (wg & 127) * 4;

    if (tid < 128) {
        msc[tid] = -2.0f * wv[tid];
        ((float4*)Eq_s)[tid] = ((const float4*)(Eq + (size_t)(b*Q_ + q0) * H_))[tid];
    }
    if (tid < 64) SL[tid >> 2][tid & 3] = 0.f;
    __syncthreads();

    const int w    = tid >> 6;
    const int lane = tid & 63;

    // ---- phase A: scores + exp + per-wave denom (EkT2 prefetch, pair-2 rcp) ----
    const int k = tid;
    if (k < n) {                             // wave-uniform (n multiple of 256)
        const float4* ekp = (const float4*)EkT2 + (size_t)(b*K_ + k);  // + h4*NK_
        float a0 = 0.f, a1 = 0.f, a2 = 0.f, a3 = 0.f;
        float4 e = ekp[0];
        #pragma unroll 4
        for (int h4 = 0; h4 < H_/4 - 1; ++h4) {
            float4 en = ekp[(size_t)(h4+1) * NK_];     // prefetch next
            QUAD(e)
            e = en;
        }
        {   // last h4 = 31
            const int h4 = H_/4 - 1;
            QUAD(e)
        }
        const bool ok = (k < valid);
        float p0 = ok ? exp2f(a0 * L2E) : 0.f;   // |score|<=2*sum|w_v| -> no max-sub
        float p1 = ok ? exp2f(a1 * L2E) : 0.f;
        float p2 = ok ? exp2f(a2 * L2E) : 0.f;
        float p3 = ok ? exp2f(a3 * L2E) : 0.f;
        S[0][k] = p0; S[1][k] = p1; S[2][k] = p2; S[3][k] = p3;
        #pragma unroll
        for (int off = 32; off > 0; off >>= 1) {
            p0 += __shfl_xor(p0, off, 64); p1 += __shfl_xor(p1, off, 64);
            p2 += __shfl_xor(p2, off, 64); p3 += __shfl_xor(p3, off, 64);
        }
        if (lane == 0) { SL[w][0] = p0; SL[w][1] = p1; SL[w][2] = p2; SL[w][3] = p3; }
    }
    __syncthreads();

    // ---- phase B: 16 k-slices, 4 rows in regs, values once, prefetched ----
    const int len = n >> 4;                  // 16..64, multiple of 16
    const int i0  = w * len;
    float4 o0 = make_float4(0,0,0,0), o1 = o0, o2 = o0, o3 = o0;
    const float4* vp = (const float4*)(values + (size_t)b * K_ * VD_);
    {
        const float4* vr = vp + (size_t)i0 * (VD_/4) + lane;
        float4 va = vr[0], vb = vr[64], vc = vr[128], vd = vr[192];
        int i = i0;
        for (; i < i0 + len - 4; i += 4) {
            const float4* vrn = vp + (size_t)(i + 4) * (VD_/4) + lane;
            float4 na = vrn[0], nb = vrn[64], nc = vrn[128], nd = vrn[192];
            PVBLK4
            va = na; vb = nb; vc = nc; vd = nd;
        }
        PVBLK4                               // final 4 keys
    }

    // ---- tree combine 16 -> 8 -> 4 -> store (race-free: self-slot rewrites) ----
    if (w >= 8) {                            // waves 8..15 -> slots 0..7
        *(float4*)&OP[w-8][0][lane][0] = o0;
        *(float4*)&OP[w-8][1][lane][0] = o1;
        *(float4*)&OP[w-8][2][lane][0] = o2;
        *(float4*)&OP[w-8][3][lane][0] = o3;
    }
    __syncthreads();
    if (w < 8) {                             // wave w adds slot w (own slot)
        ACC4(o0, (*(const float4*)&OP[w][0][lane][0]));
        ACC4(o1, (*(const float4*)&OP[w][1][lane][0]));
        ACC4(o2, (*(const float4*)&OP[w][2][lane][0]));
        ACC4(o3, (*(const float4*)&OP[w][3][lane][0]));
    }
    if (w >= 4 && w < 8) {                   // rewrite own slot (safe: self RAW)
        *(float4*)&OP[w][0][lane][0] = o0;
        *(float4*)&OP[w][1][lane][0] = o1;
        *(float4*)&OP[w][2][lane][0] = o2;
        *(float4*)&OP[w][3][lane][0] = o3;
    }
    __syncthreads();
    if (w < 4) {
        ACC4(o0, (*(const float4*)&OP[w+4][0][lane][0]));
        ACC4(o1, (*(const float4*)&OP[w+4][1][lane][0]));
        ACC4(o2, (*(const float4*)&OP[w+4][2][lane][0]));
        ACC4(o3, (*(const float4*)&OP[w+4][3][lane][0]));
        *(float4*)&OP[w][0][lane][0] = o0;   // own slot: only read by self this epoch
        *(float4*)&OP[w][1][lane][0] = o1;
        *(float4*)&OP[w][2][lane][0] = o2;
        *(float4*)&OP[w][3][lane][0] = o3;
    }
    __syncthreads();
    if (w < 4) {                             // wave w -> row w: sum 4 slots, scale, store
        const int row = w;
        float l = 0.f;
        #pragma unroll
        for (int s = 0; s < 16; ++s) l += SL[s][row];
        const float invl = arcp(l);
        float4 o = make_float4(0,0,0,0);
        #pragma unroll
        for (int s = 0; s < 4; ++s) {
            float4 p = *(const float4*)&OP[s][row][lane][0];
            o.x += p.x; o.y += p.y; o.z += p.z; o.w += p.w;
        }
        o.x *= invl; o.y *= invl; o.z *= invl; o.w *= invl;
        ((float4*)(out + (size_t)(b*Q_ + q0 + row) * VD_))[lane] = o;
    }
}

// ---------------- launch ----------------
extern "C" void kernel_launch(void* const* d_in, const int* in_sizes, int n_in,
                              void* d_out, int out_size, void* d_ws, size_t ws_size,
                              hipStream_t stream) {
    const float* queries = (const float*)d_in[0];
    const float* keys    = (const float*)d_in[1];
    const float* values  = (const float*)d_in[2];
    const int*   vlens   = (const int*)d_in[3];
    const float* W_q     = (const float*)d_in[4];
    const float* W_k     = (const float*)d_in[5];
    const float* w_v     = (const float*)d_in[6];
    float* out = (float*)d_out;
    float* ws  = (float*)d_ws;

    float* EkT2 = ws;            // (H/4) * NK_ * 4 = 524288 floats (packed)
    float* Eq   = ws + 524288;   // B*Q*H = 262144 floats

    proj_kernel<<<dim3(768), dim3(256), 0, stream>>>(keys, queries, W_k, W_q, vlens, EkT2, Eq);
    attn_kernel<<<dim3((B_*Q_)/4), dim3(1024), 0, stream>>>(Eq, EkT2, w_v, values, vlens, out);
}